// Round 9
// baseline (207.360 us; speedup 1.0000x reference)
//
#include <hip/hip_runtime.h>

// SSIM 3D loss: pred/target f32 [4,1,64,192,192], scalar 1 - mean(ssim_map).
// v19: v18 pipeline DE-CONFOUNDED. v18 bundled the 1-barrier pipeline with
//      LDS 36.4KB -> 4 blocks/CU, but the grid assigns 4-5 blocks/CU: half
//      the CUs serialized a 5th block (tail), masking the pipeline. Fixes:
//      - interm sized to the 26 rows H actually reads (was 32); stage sized
//        to the 26 rows CM actually writes; pad-init deleted (never read).
//        LDS 36.4 -> 29.4 KB -> 5 blocks/CU (covers the 4-5 assignment).
//      - W phase 512 -> 416 real tasks: the 96 pad tasks were 19% of W VALU
//        computing zero-blurs that H never reads. Round-2 guard t<416.
//      Schedule, math, and macros otherwise identical to v18 (verified).

#define D_DIM 64
#define H_DIM 192
#define W_DIM 192
#define SLICE (H_DIM * W_DIM)   // 36864
#define VOL   (D_DIM * SLICE)   // 2359296
#define NB    4
#define KS    11
#define RAD   5
#define TIL   16                // output tile 16x16
#define HLO   26                // halo extent (stage/interm rows)
#define SP2   28                // f32x2 staging pitch
#define IPP   17                // interm pitch (elements) per row
#define NPL   36                // q1 - q0, both halves
#define C1F   (0.01f * 0.01f)
#define C2F   (0.03f * 0.03f)

typedef float f32x2 __attribute__((ext_vector_type(2)));

// LDS-only barrier: order LDS ops, leave global loads (vmcnt) in flight.
#define BAR_LDS() do {                                                    \
    asm volatile("s_waitcnt lgkmcnt(0)" ::: "memory");                    \
    __builtin_amdgcn_s_barrier();                                         \
    __builtin_amdgcn_sched_barrier(0);                                    \
} while (0)

__device__ __forceinline__ void make_window(float* g) {
    float s = 0.f;
#pragma unroll
    for (int i = 0; i < KS; ++i) {
        float c = (float)(i - RAD);
        g[i] = expf(-(c * c) * (1.0f / 4.5f));  // 2*sigma^2 = 4.5
        s += g[i];
    }
    float inv = 1.0f / s;
#pragma unroll
    for (int i = 0; i < KS; ++i) g[i] *= inv;
}

#define SSIM_ACC(MP, MT, E2, T2, PT) do {                                 \
    float _mps = (MP) * (MP), _mts = (MT) * (MT), _mpt = (MP) * (MT);     \
    float _num = (2.f * _mpt + C1F) * (2.f * ((PT) - _mpt) + C2F);        \
    float _den = (_mps + _mts + C1F) *                                    \
                 (((E2) - _mps) + ((T2) - _mts) + C2F);                   \
    ssim_sum += _num * __builtin_amdgcn_rcpf(_den);                       \
} while (0)

// ---- pipeline phase macros (i = iteration index) ----
// commit plane q0+i from prefetch regs into S[i&1]
#define CM(i) do {                                                        \
    f32x2* _s = Sb[(i) & 1];                                              \
    _Pragma("unroll")                                                     \
    for (int _k = 0; _k < 3; ++_k)                                        \
        if (sa[_k]) _s[slds[_k]] = (f32x2){rp[_k], rt[_k]};               \
} while (0)

// prefetch plane q0+i+1 into regs (in flight across barriers)
#define PF(i) do {                                                        \
    const float* _pn = pb + (q0 + (i) + 1) * SLICE;                       \
    const float* _tn = tb + (q0 + (i) + 1) * SLICE;                       \
    _Pragma("unroll")                                                     \
    for (int _k = 0; _k < 3; ++_k) {                                      \
        rp[_k] = sv[_k] ? _pn[sidx[_k]] : 0.f;                            \
        rt[_k] = sv[_k] ? _tn[sidx[_k]] : 0.f;                            \
    }                                                                     \
} while (0)

// W-blur plane q0+i-1: read S[(i-1)&1] -> write I*[(i-1)&1] (416 real tasks)
#define WPH(i) do {                                                       \
    const int _b = ((i) - 1) & 1;                                         \
    const f32x2* _sp = Sb[_b];                                            \
    _Pragma("unroll")                                                     \
    for (int _it = 0; _it < 2; ++_it) {                                   \
        int _t = tid + _it * 256;                                         \
        if (_t < HLO * TIL) {                                             \
            int _r = _t >> 4, _c = _t & 15;                               \
            const f32x2* _pr = _sp + _r * SP2 + _c;                       \
            f32x2 _s01 = (f32x2){0.f, 0.f};                               \
            f32x2 _s23 = (f32x2){0.f, 0.f};                               \
            float _s4 = 0.f;                                              \
            _Pragma("unroll")                                             \
            for (int _k = 0; _k < KS; ++_k) {                             \
                f32x2 _v = _pr[_k];                                       \
                float _gk = g[_k];                                        \
                f32x2 _g2 = (f32x2){_gk, _gk};                            \
                _s01 += _g2 * _v;                                         \
                _s23 += _g2 * (_v * _v);                                  \
                _s4 += _gk * (_v.x * _v.y);                               \
            }                                                             \
            int _oi = _r * IPP + _c;                                      \
            I01b[_b][_oi] = _s01;                                         \
            I23b[_b][_oi] = _s23;                                         \
            I4b [_b][_oi] = _s4;                                          \
        }                                                                 \
    }                                                                     \
} while (0)

// H-blur + D-accum + emit for plane q0+i-2: read I*[i&1]
#define HPH(i) do {                                                       \
    const int _b = (i) & 1;                                               \
    const f32x2* _c01 = I01b[_b] + px;                                    \
    const f32x2* _c23 = I23b[_b] + px;                                    \
    const float* _c4  = I4b [_b] + px;                                    \
    f32x2 _v01 = (f32x2){0.f, 0.f};                                       \
    f32x2 _v23 = (f32x2){0.f, 0.f};                                       \
    float _v4 = 0.f;                                                      \
    _Pragma("unroll")                                                     \
    for (int _k = 0; _k < KS; ++_k) {                                     \
        int _rr = (py + _k) * IPP;                                        \
        float _gk = g[_k];                                                \
        f32x2 _g2 = (f32x2){_gk, _gk};                                    \
        _v01 += _g2 * _c01[_rr];                                          \
        _v23 += _g2 * _c23[_rr];                                          \
        _v4 += _gk * _c4[_rr];                                            \
    }                                                                     \
    _Pragma("unroll")                                                     \
    for (int _j = 0; _j < KS; ++_j) {                                     \
        float _wj = g[10 - _j];                                           \
        f32x2 _w2 = (f32x2){_wj, _wj};                                    \
        a01[_j] += _w2 * _v01;                                            \
        a23[_j] += _w2 * _v23;                                            \
        a4[_j] += _wj * _v4;                                              \
    }                                                                     \
    if (q0 + (i) - 7 >= d_lo)                                             \
        SSIM_ACC(a01[0].x, a01[0].y, a23[0].x, a23[0].y, a4[0]);          \
    _Pragma("unroll")                                                     \
    for (int _j = 0; _j < KS - 1; ++_j) {                                 \
        a01[_j] = a01[_j + 1]; a23[_j] = a23[_j + 1]; a4[_j] = a4[_j + 1];\
    }                                                                     \
    a01[10] = (f32x2){0.f, 0.f};                                          \
    a23[10] = (f32x2){0.f, 0.f};                                          \
    a4[10] = 0.f;                                                         \
} while (0)

__global__ __launch_bounds__(256) void fused_ssim_kernel(
    const float* __restrict__ pred, const float* __restrict__ targ,
    float* __restrict__ partials) {
    __shared__ f32x2 Sb[2][HLO * SP2];               // 11648 B
    __shared__ f32x2 I01b[2][HLO * IPP];             // 7072 B
    __shared__ f32x2 I23b[2][HLO * IPP];             // 7072 B
    __shared__ float I4b[2][HLO * IPP];              // 3536 B
    __shared__ float red[4];                         // total ~29.4 KB

    float g[KS];
    make_window(g);

    const int tid = threadIdx.x;
    const int h0 = (blockIdx.x / 12) * TIL;
    const int w0 = (blockIdx.x % 12) * TIL;
    const int half = blockIdx.y;
    const float* pb = pred + (size_t)blockIdx.z * VOL;
    const float* tb = targ + (size_t)blockIdx.z * VOL;
    const int q0 = half ? 27 : 0;                    // first plane
    const int d_lo = half ? 32 : 0;
    const int d_hi = half ? 63 : 31;

    // ---- plane-invariant staging precompute (676 halo px, 3 strides) ----
    int sidx[3], slds[3];
    bool sa[3], sv[3];
#pragma unroll
    for (int k = 0; k < 3; ++k) {
        int i = tid + 256 * k;
        sa[k] = i < HLO * HLO;
        int y = i / HLO, x = i - y * HLO;
        int gh = h0 + y - RAD, gw = w0 + x - RAD;
        sv[k] = sa[k] && (unsigned)gh < (unsigned)H_DIM &&
                (unsigned)gw < (unsigned)W_DIM;
        sidx[k] = gh * W_DIM + gw;
        slds[k] = y * SP2 + x;
    }
    const int py = tid >> 4, px = tid & 15;          // H-phase pixel

    // ---- D-window accumulators: slot j = output d = p + j - 5 ----
    f32x2 a01[KS], a23[KS];
    float a4[KS];
#pragma unroll
    for (int j = 0; j < KS; ++j) {
        a01[j] = (f32x2){0.f, 0.f};
        a23[j] = (f32x2){0.f, 0.f};
        a4[j] = 0.f;
    }
    float ssim_sum = 0.f;

    // prologue: load plane q0 into regs
    float rp[3], rt[3];
    {
        const float* pq = pb + q0 * SLICE;
        const float* tq = tb + q0 * SLICE;
#pragma unroll
        for (int k = 0; k < 3; ++k) {
            rp[k] = sv[k] ? pq[sidx[k]] : 0.f;
            rt[k] = sv[k] ? tq[sidx[k]] : 0.f;
        }
    }

    // ---- pipeline: iter i runs CM(i) || W(i-1) || H(i-2), one barrier ----
    CM(0); PF(0); BAR_LDS();                         // i = 0
    CM(1); PF(1); WPH(1); BAR_LDS();                 // i = 1
    for (int i = 2; i <= NPL - 1; ++i) {             // i = 2..35 (uniform)
        CM(i); PF(i); WPH(i); HPH(i); BAR_LDS();
    }
    CM(NPL); WPH(NPL); HPH(NPL); BAR_LDS();          // i = 36 (no prefetch)
    WPH(NPL + 1); HPH(NPL + 1); BAR_LDS();           // i = 37 (no commit)
    HPH(NPL + 2);                                    // i = 38 (drain)

    // ---- tail: outputs d = q1-4 .. q1 (zero-padded D windows; the d<=d_hi
    //      gate makes half0 emit nothing, half1 emit d=59..63) ----
#pragma unroll
    for (int j = 0; j < 5; ++j) {
        int d = q0 + NPL - 4 + j;
        if (d >= d_lo && d <= d_hi)
            SSIM_ACC(a01[j].x, a01[j].y, a23[j].x, a23[j].y, a4[j]);
    }

    // ---- block reduction ----
    float a = ssim_sum;
#pragma unroll
    for (int off = 32; off > 0; off >>= 1) a += __shfl_down(a, off, 64);
    int lane = tid & 63, wv = tid >> 6;
    if (lane == 0) red[wv] = a;
    __syncthreads();
    if (tid == 0)
        partials[((blockIdx.z * 2 + blockIdx.y) * 144) + blockIdx.x] =
            red[0] + red[1] + red[2] + red[3];
}

// ---- final reduction ----
__global__ __launch_bounds__(256) void finalize_kernel(
    const float* __restrict__ partials, int n, float* __restrict__ out) {
    double a = 0.0;
    for (int i = threadIdx.x; i < n; i += 256) a += (double)partials[i];
#pragma unroll
    for (int off = 32; off > 0; off >>= 1) a += __shfl_down(a, off, 64);
    __shared__ double red[4];
    int lane = threadIdx.x & 63, wv = threadIdx.x >> 6;
    if (lane == 0) red[wv] = a;
    __syncthreads();
    if (threadIdx.x == 0) {
        double s = red[0] + red[1] + red[2] + red[3];
        out[0] = (float)(1.0 - s / (double)((long long)NB * VOL));
    }
}

extern "C" void kernel_launch(void* const* d_in, const int* in_sizes, int n_in,
                              void* d_out, int out_size, void* d_ws, size_t ws_size,
                              hipStream_t stream) {
    const float* pred = (const float*)d_in[0];
    const float* targ = (const float*)d_in[1];
    float* out = (float*)d_out;
    float* partials = (float*)d_ws;                  // NB*288 floats

    fused_ssim_kernel<<<dim3(144, 2, NB), 256, 0, stream>>>(pred, targ, partials);
    finalize_kernel<<<1, 256, 0, stream>>>(partials, NB * 288, out);
}